// Round 1
// baseline (48.810 us; speedup 1.0000x reference)
//
#include <hip/hip_runtime.h>
#include <hip/hip_bf16.h>

#define NBINS 32
#define CHUNK 256           // voxels staged per chunk
#define LDS_STRIDE 264      // 256 + 8 pad elements -> 528B row stride (2-way LDS conflict = free)
#define NTHREADS 256
#define BLOCKS_PER_BATCH 432
#define CHUNKS_PER_BLOCK 8  // 432 * 8 * 256 = 884736 exactly
#define NVOX 884736         // 96^3

typedef __attribute__((ext_vector_type(8))) _Float16 half8;
typedef __attribute__((ext_vector_type(4))) float f32x4;
typedef __attribute__((ext_vector_type(4))) int i32x4;

// Parzen: preterm = 1/(2*sigma^2), sigma = 0.5/31  ->  exponent in bin units: -2*(u-o)^2

__device__ __forceinline__ void scatter_weights(_Float16* __restrict__ L, int tid, float x) {
    float tt = x * 31.0f;
    float kf = rintf(tt);
    int ki = (int)kf;
    float u = tt - kf;               // [-0.5, 0.5]
    float w[9];
    float s = 0.0f;
#pragma unroll
    for (int o = 0; o < 9; ++o) {
        float d = u - (float)(o - 4);
        float e = __expf(-2.0f * d * d);
        int b = ki + o - 4;
        bool valid = (b >= 0) && (b < NBINS);
        e = valid ? e : 0.0f;
        w[o] = e;
        s += e;
    }
    float rinv = 1.0f / s;
#pragma unroll
    for (int o = 0; o < 9; ++o) {
        int b = ki + o - 4;
        if (b >= 0 && b < NBINS)
            L[b * LDS_STRIDE + tid] = (_Float16)(w[o] * rinv);
    }
}

__global__ __launch_bounds__(NTHREADS)
void mi_hist_kernel(const float* __restrict__ pred, const float* __restrict__ targ,
                    float* __restrict__ hist /* [2][32][32] */) {
    __shared__ __attribute__((aligned(16))) _Float16 smem[2 * NBINS * LDS_STRIDE];
    _Float16* LA = smem;
    _Float16* LB = smem + NBINS * LDS_STRIDE;

    const int tid = threadIdx.x;
    const int bx = blockIdx.x;
    const int batch = blockIdx.y;
    const float* p = pred + (size_t)batch * NVOX;
    const float* t = targ + (size_t)batch * NVOX;

    const int wid = tid >> 6;
    const int lane = tid & 63;
    const int wi = wid >> 1;         // A-row block (pred-bin quadrant)
    const int wj = wid & 1;          // B-col block (target-bin quadrant)
    const int a_off = (wi * 16 + (lane & 15)) * LDS_STRIDE + 8 * (lane >> 4);
    const int b_off = (wj * 16 + (lane & 15)) * LDS_STRIDE + 8 * (lane >> 4);

    f32x4 acc = {0.0f, 0.0f, 0.0f, 0.0f};

    for (int c = 0; c < CHUNKS_PER_BLOCK; ++c) {
        const int v0 = (bx * CHUNKS_PER_BLOCK + c) * CHUNK;
        __syncthreads();  // previous chunk's MFMA reads finished before we overwrite LDS
        // zero-fill both tiles: 2*32*264 halfs = 33792 B = 2112 x 16B
        i32x4* z = (i32x4*)smem;
        for (int i = tid; i < 2112; i += NTHREADS) z[i] = (i32x4){0, 0, 0, 0};
        __syncthreads();
        scatter_weights(LA, tid, p[v0 + tid]);
        scatter_weights(LB, tid, t[v0 + tid]);
        __syncthreads();
#pragma unroll
        for (int kb = 0; kb < CHUNK / 32; ++kb) {
            half8 af = *(const half8*)&LA[a_off + kb * 32];
            half8 bf = *(const half8*)&LB[b_off + kb * 32];
            acc = __builtin_amdgcn_mfma_f32_16x16x32_f16(af, bf, acc, 0, 0, 0);
        }
    }

    // C/D layout (gfx950 16x16x32): col = lane&15, row = (lane>>4)*4 + reg
    const int col = wj * 16 + (lane & 15);
    const int rbase = wi * 16 + (lane >> 4) * 4;
#pragma unroll
    for (int r = 0; r < 4; ++r) {
        atomicAdd(&hist[(batch * NBINS + (rbase + r)) * NBINS + col], acc[r]);
    }
}

__global__ void mi_reduce_kernel(const float* __restrict__ hist, float* __restrict__ out) {
    __shared__ double s_pa[2][NBINS];
    __shared__ double s_pb[2][NBINS];
    __shared__ double s_red[256];
    const int tid = threadIdx.x;
    const double invN = 1.0 / (double)NVOX;

    if (tid < 64) {
        int b = tid >> 5, i = tid & 31;
        double s = 0.0;
        for (int j = 0; j < NBINS; ++j) s += (double)hist[(b * NBINS + i) * NBINS + j];
        s_pa[b][i] = s * invN;
    } else if (tid < 128) {
        int t2 = tid - 64;
        int b = t2 >> 5, j = t2 & 31;
        double s = 0.0;
        for (int i = 0; i < NBINS; ++i) s += (double)hist[(b * NBINS + i) * NBINS + j];
        s_pb[b][j] = s * invN;
    }
    __syncthreads();

    double acc = 0.0;
    for (int idx = tid; idx < 2 * NBINS * NBINS; idx += 256) {
        int b = idx >> 10;
        int cell = idx & 1023;
        int i = cell >> 5, j = cell & 31;
        double pab = (double)hist[idx] * invN;
        double papb = s_pa[b][i] * s_pb[b][j];
        acc += pab * log((pab + 1e-7) / (papb + 1e-7) + 1e-7);
    }
    s_red[tid] = acc;
    __syncthreads();
    for (int s2 = 128; s2 > 0; s2 >>= 1) {
        if (tid < s2) s_red[tid] += s_red[tid + s2];
        __syncthreads();
    }
    if (tid == 0) out[0] = (float)(-0.5 * s_red[0]);
}

extern "C" void kernel_launch(void* const* d_in, const int* in_sizes, int n_in,
                              void* d_out, int out_size, void* d_ws, size_t ws_size,
                              hipStream_t stream) {
    const float* pred = (const float*)d_in[0];
    const float* targ = (const float*)d_in[1];
    float* hist = (float*)d_ws;
    float* out = (float*)d_out;

    hipMemsetAsync(hist, 0, 2 * NBINS * NBINS * sizeof(float), stream);
    dim3 grid(BLOCKS_PER_BATCH, 2);
    hipLaunchKernelGGL(mi_hist_kernel, grid, dim3(NTHREADS), 0, stream, pred, targ, hist);
    hipLaunchKernelGGL(mi_reduce_kernel, dim3(1), dim3(256), 0, stream, hist, out);
}

// Round 2
// 44.992 us; speedup vs baseline: 1.0849x; 1.0849x over previous
//
#include <hip/hip_runtime.h>
#include <hip/hip_bf16.h>

#define NBINS 32
#define LDS_STRIDE 264      // 256 + 8 pad halfs -> 528B row stride (4-bank shift/row, conflict-free b128 reads)
#define NTHREADS 256
#define NVOX 884736         // 96^3 = 3456 * 256
#define NSLABS 3456         // 256-voxel slabs per batch
#define BLOCKS_PER_BATCH 256
#define BUF_HALVES (2 * NBINS * LDS_STRIDE)   // A tile + B tile = 16896 halfs = 33792 B

typedef __attribute__((ext_vector_type(8))) _Float16 half8;
typedef __attribute__((ext_vector_type(4))) float f32x4;
typedef __attribute__((ext_vector_type(4))) int i32x4;

// Parzen: preterm = 1/(2*sigma^2), sigma = 0.5/31 -> exponent in bin units: -2*(tt-o)^2
// NOTE: numerics kept byte-identical to the passing round-1 kernel.
__device__ __forceinline__ void scatter_weights(_Float16* __restrict__ L, int tid, float x) {
    float tt = x * 31.0f;
    float kf = rintf(tt);
    int ki = (int)kf;
    float u = tt - kf;               // [-0.5, 0.5]
    float w[9];
    float s = 0.0f;
#pragma unroll
    for (int o = 0; o < 9; ++o) {
        float d = u - (float)(o - 4);
        float e = __expf(-2.0f * d * d);
        int b = ki + o - 4;
        bool valid = (b >= 0) && (b < NBINS);
        e = valid ? e : 0.0f;
        w[o] = e;
        s += e;
    }
    float rinv = 1.0f / s;
#pragma unroll
    for (int o = 0; o < 9; ++o) {
        int b = ki + o - 4;
        if (b >= 0 && b < NBINS)
            L[b * LDS_STRIDE + tid] = (_Float16)(w[o] * rinv);
    }
}

__global__ __launch_bounds__(NTHREADS)
void mi_hist_kernel(const float* __restrict__ pred, const float* __restrict__ targ,
                    float* __restrict__ hist /* [2][32][32] */) {
    // double-buffered: [2 buffers][A tile | B tile]
    __shared__ __attribute__((aligned(16))) _Float16 smem[2 * BUF_HALVES];

    const int tid = threadIdx.x;
    const int bx = blockIdx.x;
    const int batch = blockIdx.y;
    const float* p = pred + (size_t)batch * NVOX;
    const float* t = targ + (size_t)batch * NVOX;

    const int wid = tid >> 6;
    const int lane = tid & 63;
    const int wi = wid >> 1;         // pred-bin quadrant
    const int wj = wid & 1;          // target-bin quadrant
    const int a_off = (wi * 16 + (lane & 15)) * LDS_STRIDE + 8 * (lane >> 4);
    const int b_off = (wj * 16 + (lane & 15)) * LDS_STRIDE + 8 * (lane >> 4) + NBINS * LDS_STRIDE;

    // slab index for chunk c is c*BLOCKS_PER_BATCH + bx; valid while < NSLABS.
    // 3456 = 13*256 + 128 -> blocks 0..127 run 14 chunks, 128..255 run 13. Block-uniform.
    const int nchunks = (bx < 128) ? 14 : 13;

    f32x4 acc = {0.0f, 0.0f, 0.0f, 0.0f};

    // prologue: zero buffer 0, prefetch chunk 0 values
    {
        i32x4* z = (i32x4*)smem;
        for (int i = tid; i < BUF_HALVES / 8; i += NTHREADS) z[i] = (i32x4){0, 0, 0, 0};
    }
    float pv = p[(size_t)bx * 256 + tid];
    float tv = t[(size_t)bx * 256 + tid];
    __syncthreads();

    for (int c = 0; c < nchunks; ++c) {
        const int cur = c & 1;
        _Float16* buf = smem + cur * BUF_HALVES;

        // prefetch next chunk's values + zero next buffer (overlaps this chunk's scatter)
        float pn = 0.0f, tn = 0.0f;
        if (c + 1 < nchunks) {
            size_t v = ((size_t)(c + 1) * BLOCKS_PER_BATCH + bx) * 256 + tid;
            pn = p[v];
            tn = t[v];
            i32x4* z = (i32x4*)(smem + (cur ^ 1) * BUF_HALVES);
            for (int i = tid; i < BUF_HALVES / 8; i += NTHREADS) z[i] = (i32x4){0, 0, 0, 0};
        }

        scatter_weights(buf, tid, pv);                         // A tile
        scatter_weights(buf + NBINS * LDS_STRIDE, tid, tv);    // B tile
        __syncthreads();   // scatter visible to all waves

#pragma unroll
        for (int kb = 0; kb < 256 / 32; ++kb) {
            half8 af = *(const half8*)&buf[a_off + kb * 32];
            half8 bf = *(const half8*)&buf[b_off + kb * 32];
            acc = __builtin_amdgcn_mfma_f32_16x16x32_f16(af, bf, acc, 0, 0, 0);
        }
        __syncthreads();   // MFMA reads done before this buffer is zeroed next+1 iter

        pv = pn; tv = tn;
    }

    // C/D layout (gfx950 16x16x32): col = lane&15, row = (lane>>4)*4 + reg
    const int col = wj * 16 + (lane & 15);
    const int rbase = wi * 16 + (lane >> 4) * 4;
#pragma unroll
    for (int r = 0; r < 4; ++r) {
        atomicAdd(&hist[(batch * NBINS + (rbase + r)) * NBINS + col], acc[r]);
    }
}

__global__ void mi_reduce_kernel(const float* __restrict__ hist, float* __restrict__ out) {
    __shared__ double s_pa[2][NBINS];
    __shared__ double s_pb[2][NBINS];
    __shared__ double s_red[256];
    const int tid = threadIdx.x;
    const double invN = 1.0 / (double)NVOX;

    if (tid < 64) {
        int b = tid >> 5, i = tid & 31;
        double s = 0.0;
        for (int j = 0; j < NBINS; ++j) s += (double)hist[(b * NBINS + i) * NBINS + j];
        s_pa[b][i] = s * invN;
    } else if (tid < 128) {
        int t2 = tid - 64;
        int b = t2 >> 5, j = t2 & 31;
        double s = 0.0;
        for (int i = 0; i < NBINS; ++i) s += (double)hist[(b * NBINS + i) * NBINS + j];
        s_pb[b][j] = s * invN;
    }
    __syncthreads();

    double acc = 0.0;
    for (int idx = tid; idx < 2 * NBINS * NBINS; idx += 256) {
        int b = idx >> 10;
        int cell = idx & 1023;
        int i = cell >> 5, j = cell & 31;
        double pab = (double)hist[idx] * invN;
        double papb = s_pa[b][i] * s_pb[b][j];
        acc += pab * log((pab + 1e-7) / (papb + 1e-7) + 1e-7);
    }
    s_red[tid] = acc;
    __syncthreads();
    for (int s2 = 128; s2 > 0; s2 >>= 1) {
        if (tid < s2) s_red[tid] += s_red[tid + s2];
        __syncthreads();
    }
    if (tid == 0) out[0] = (float)(-0.5 * s_red[0]);
}

extern "C" void kernel_launch(void* const* d_in, const int* in_sizes, int n_in,
                              void* d_out, int out_size, void* d_ws, size_t ws_size,
                              hipStream_t stream) {
    const float* pred = (const float*)d_in[0];
    const float* targ = (const float*)d_in[1];
    float* hist = (float*)d_ws;
    float* out = (float*)d_out;

    hipMemsetAsync(hist, 0, 2 * NBINS * NBINS * sizeof(float), stream);
    dim3 grid(BLOCKS_PER_BATCH, 2);
    hipLaunchKernelGGL(mi_hist_kernel, grid, dim3(NTHREADS), 0, stream, pred, targ, hist);
    hipLaunchKernelGGL(mi_reduce_kernel, dim3(1), dim3(256), 0, stream, hist, out);
}